// Round 1
// baseline (587.956 us; speedup 1.0000x reference)
//
#include <hip/hip_runtime.h>
#include <math.h>

#define BB 2
#define TT 512
#define CC 64
#define HH 64

// ---------------------------------------------------------------------------
// Kernel A: kp = (x+pos) @ W1k, qp = (x+pos) @ W1q, v = x @ Wv + bv
// grid = B*T blocks of 64 threads; thread c computes channel c of each row.
// ---------------------------------------------------------------------------
__global__ __launch_bounds__(64) void prep_kernel(
    const float* __restrict__ x, const float* __restrict__ pos_emb,
    const float* __restrict__ W1, const float* __restrict__ Wv,
    const float* __restrict__ bv,
    float* __restrict__ kp, float* __restrict__ qp, float* __restrict__ v)
{
    const int row = blockIdx.x;          // b*T + t
    const int t = row & (TT - 1);
    const int c = threadIdx.x;           // 0..63
    __shared__ float xs[CC], x1s[CC];
    float xv = x[row * CC + c];
    xs[c] = xv;
    x1s[c] = xv + pos_emb[t * CC + c];
    __syncthreads();
    float ak = 0.f, aq = 0.f, av = 0.f;
#pragma unroll 8
    for (int k = 0; k < CC; ++k) {
        ak = fmaf(x1s[k], W1[k * CC + c], ak);          // W1k rows 0..C-1
        aq = fmaf(x1s[k], W1[(CC + k) * CC + c], aq);   // W1q rows C..2C-1
        av = fmaf(xs[k], Wv[k * HH + c], av);
    }
    kp[row * CC + c] = ak;
    qp[row * CC + c] = aq;
    v[row * HH + c] = av + bv[c];
}

// ---------------------------------------------------------------------------
// Kernel B: causal wei logits.
// wei[b,i,j] = (sum_c gelu(pp[b,i,j,c] + qp[b,i,c] + kp[b,j,c] + b1[c]) * W2[c]
//              + b2) * C^-0.5     for j <= i
// pp[b,i,j,c] = sum_k pd[b,i,j,k] * W1p[k,c]   (K = 2C = 128)
//
// M-parallel: lane owns one j, accumulates all 64 channels in VGPRs.
// W1p / qp / b1 / W2 indices are wave-uniform -> scalar loads.
// No LDS, no barriers -> waves early-exit independently (causal).
// ---------------------------------------------------------------------------
__global__ __launch_bounds__(256) void wei_kernel(
    const float* __restrict__ pd, const float* __restrict__ W1,
    const float* __restrict__ b1, const float* __restrict__ W2,
    const float* __restrict__ b2, const float* __restrict__ kp,
    const float* __restrict__ qp, float* __restrict__ wei)
{
    const int i = blockIdx.y;
    const int b = blockIdx.z;
    const int j = blockIdx.x * 256 + threadIdx.x;
    const int jw = j & ~63;              // wave's first j (wave-uniform)
    if (jw > i) return;                  // whole-wave exit, no barriers used
    const bool active = (j <= i);
    const int jc = active ? j : i;       // clamp for safe loads

    const float* __restrict__ Wp = W1 + 2 * CC * CC;   // W1p rows 2C..4C-1
    const float* __restrict__ pdrow = pd + (((size_t)b * TT + i) * TT + jc) * (2 * CC);

    float acc[CC];
#pragma unroll
    for (int c = 0; c < CC; ++c) acc[c] = 0.f;

    const float4* __restrict__ pd4 = (const float4*)pdrow;
    for (int k0 = 0; k0 < 2 * CC; k0 += 4) {
        float4 p = pd4[k0 / 4];
#pragma unroll
        for (int dk = 0; dk < 4; ++dk) {
            const float pk = (dk == 0) ? p.x : (dk == 1) ? p.y : (dk == 2) ? p.z : p.w;
            const float* __restrict__ wrow = Wp + (k0 + dk) * CC;
#pragma unroll
            for (int c = 0; c < CC; ++c)
                acc[c] = fmaf(pk, wrow[c], acc[c]);     // wrow[c] wave-uniform -> s_load
        }
    }

    const float* __restrict__ kprow = kp + ((size_t)b * TT + jc) * CC;  // per-lane
    const float* __restrict__ qprow = qp + ((size_t)b * TT + i) * CC;   // uniform
    float s = 0.f;
#pragma unroll
    for (int c = 0; c < CC; ++c) {
        float tv = acc[c] + qprow[c] + kprow[c] + b1[c];
        float g = 0.5f * tv * (1.f + erff(tv * 0.70710678118654752f));  // exact gelu
        s = fmaf(g, W2[c], s);
    }
    if (active)
        wei[((size_t)b * TT + i) * TT + j] = (s + b2[0]) * 0.125f;  // 64^-0.5
}

// ---------------------------------------------------------------------------
// Kernel C: causal softmax over j in [0,i], then out[b,i,:] = p @ v
// grid = (T, B), block = 256 (4 waves). Row length <= 512.
// ---------------------------------------------------------------------------
__device__ inline float wave_reduce_max(float m) {
#pragma unroll
    for (int off = 32; off > 0; off >>= 1) m = fmaxf(m, __shfl_down(m, off));
    return m;
}
__device__ inline float wave_reduce_sum(float s) {
#pragma unroll
    for (int off = 32; off > 0; off >>= 1) s += __shfl_down(s, off);
    return s;
}

__global__ __launch_bounds__(256) void out_kernel(
    const float* __restrict__ wei, const float* __restrict__ v,
    float* __restrict__ out)
{
    const int i = blockIdx.x;
    const int b = blockIdx.y;
    const int tid = threadIdx.x;
    const int wv = tid >> 6;          // wave id 0..3
    const int lane = tid & 63;
    const int n = i + 1;

    __shared__ float p[TT];
    __shared__ float red[4];
    __shared__ float part[4][HH];

    // --- max ---
    float m = -1e30f;
    for (int jj = tid; jj < n; jj += 256) {
        float w = wei[((size_t)b * TT + i) * TT + jj];
        p[jj] = w;
        m = fmaxf(m, w);
    }
    m = wave_reduce_max(m);
    if (lane == 0) red[wv] = m;
    __syncthreads();
    const float M = fmaxf(fmaxf(red[0], red[1]), fmaxf(red[2], red[3]));
    __syncthreads();

    // --- exp + sum ---
    float s = 0.f;
    for (int jj = tid; jj < n; jj += 256) {
        float e = __expf(p[jj] - M);
        p[jj] = e;
        s += e;
    }
    s = wave_reduce_sum(s);
    if (lane == 0) red[wv] = s;
    __syncthreads();
    const float S = red[0] + red[1] + red[2] + red[3];
    const float inv = 1.f / S;

    // --- p @ v : lane = h channel, wave strides over j ---
    float acc = 0.f;
    for (int jj = wv; jj < n; jj += 4)
        acc = fmaf(p[jj], v[((size_t)b * TT + jj) * HH + lane], acc);
    part[wv][lane] = acc;
    __syncthreads();
    if (tid < HH) {
        float r = (part[0][tid] + part[1][tid] + part[2][tid] + part[3][tid]) * inv;
        out[((size_t)b * TT + i) * HH + tid] = r;
    }
}

// ---------------------------------------------------------------------------
extern "C" void kernel_launch(void* const* d_in, const int* in_sizes, int n_in,
                              void* d_out, int out_size, void* d_ws, size_t ws_size,
                              hipStream_t stream)
{
    const float* x       = (const float*)d_in[0];
    const float* pos_emb = (const float*)d_in[1];
    const float* pd      = (const float*)d_in[2];
    const float* W1      = (const float*)d_in[3];
    const float* b1      = (const float*)d_in[4];
    const float* W2      = (const float*)d_in[5];
    const float* b2      = (const float*)d_in[6];
    const float* Wv      = (const float*)d_in[7];
    const float* bv      = (const float*)d_in[8];
    float* out = (float*)d_out;

    float* ws = (float*)d_ws;
    float* kp  = ws;                       // B*T*C = 65536 floats
    float* qp  = ws + 65536;               // 65536
    float* v   = ws + 131072;              // B*T*H = 65536
    float* wei = ws + 196608;              // B*T*T = 524288

    prep_kernel<<<dim3(BB * TT), dim3(64), 0, stream>>>(x, pos_emb, W1, Wv, bv, kp, qp, v);
    wei_kernel<<<dim3(TT / 256, TT, BB), dim3(256), 0, stream>>>(pd, W1, b1, W2, b2, kp, qp, wei);
    out_kernel<<<dim3(TT, BB), dim3(256), 0, stream>>>(wei, v, out);
}

// Round 2
// 404.775 us; speedup vs baseline: 1.4526x; 1.4526x over previous
//
#include <hip/hip_runtime.h>
#include <math.h>

#define BB 2
#define TT 512
#define CC 64
#define HH 64
#define KK 128            // 2C
#define PADK 136          // bf16 row stride in LDS/ws (pad +8 -> bank spread)
#define JT 64             // j-tile per block

typedef __attribute__((ext_vector_type(8))) short short8;
typedef __attribute__((ext_vector_type(4))) float float4v;

__device__ inline unsigned short f2bf(float f) {
    unsigned int u = __float_as_uint(f);
    u = (u + 0x7FFFu + ((u >> 16) & 1u)) >> 16;   // RNE
    return (unsigned short)u;
}

// ---------------------------------------------------------------------------
// pack_kernel: Wpt[c][k] = bf16(W1p[k][c]), padded rows of PADK, into ws.
// 8192 elements, trivial.
// ---------------------------------------------------------------------------
__global__ __launch_bounds__(256) void pack_kernel(
    const float* __restrict__ W1, unsigned short* __restrict__ Wpt)
{
    int t = blockIdx.x * 256 + threadIdx.x;     // 0..8191
    int c = t >> 7;                             // 0..63
    int k = t & 127;                            // 0..127
    Wpt[c * PADK + k] = f2bf(W1[(2 * CC + k) * CC + c]);
}

// ---------------------------------------------------------------------------
// prep: kp = (x+pos)@W1k ; qpb = (x+pos)@W1q + b1 ; v = x@Wv + bv
// ---------------------------------------------------------------------------
__global__ __launch_bounds__(64) void prep_kernel(
    const float* __restrict__ x, const float* __restrict__ pos_emb,
    const float* __restrict__ W1, const float* __restrict__ b1,
    const float* __restrict__ Wv, const float* __restrict__ bv,
    float* __restrict__ kp, float* __restrict__ qpb, float* __restrict__ v)
{
    const int row = blockIdx.x;          // b*T + t
    const int t = row & (TT - 1);
    const int c = threadIdx.x;           // 0..63
    __shared__ float xs[CC], x1s[CC];
    float xv = x[row * CC + c];
    xs[c] = xv;
    x1s[c] = xv + pos_emb[t * CC + c];
    __syncthreads();
    float ak = 0.f, aq = 0.f, av = 0.f;
#pragma unroll 8
    for (int k = 0; k < CC; ++k) {
        ak = fmaf(x1s[k], W1[k * CC + c], ak);
        aq = fmaf(x1s[k], W1[(CC + k) * CC + c], aq);
        av = fmaf(xs[k], Wv[k * HH + c], av);
    }
    kp[row * CC + c] = ak;
    qpb[row * CC + c] = aq + b1[c];
    v[row * HH + c] = av + bv[c];
}

// ---------------------------------------------------------------------------
// wei_kernel v2: bf16 MFMA.
// Block = (b, i, j-tile of 64). K=128 fits LDS in one shot.
//   A = pd[b,i, j0..j0+63, :]  (fp32 -> bf16 in LDS, row pad +8)
//   B = Wpt (pre-packed transposed bf16 W1p from ws)
// 4 waves x 16 j-rows each; 4x4 MFMA 16x16x32 per wave.
// Epilogue: tv = pp + qpb[i,c] + kp[j,c]; gelu; dot W2 via 16-lane butterfly.
// ---------------------------------------------------------------------------
__global__ __launch_bounds__(256) void wei_kernel(
    const float* __restrict__ pd, const unsigned short* __restrict__ Wpt,
    const float* __restrict__ W2, const float* __restrict__ b2,
    const float* __restrict__ kp, const float* __restrict__ qpb,
    float* __restrict__ wei)
{
    const int i = blockIdx.y;
    const int b = blockIdx.z;
    const int j0 = blockIdx.x * JT;
    if (j0 > i) return;                  // uniform early exit (before barriers)

    __shared__ unsigned short Alds[JT * PADK];   // 17408 B
    __shared__ unsigned short Blds[CC * PADK];   // 17408 B

    const int tid = threadIdx.x;

    // ---- stage B: straight 16B copy of padded bf16 image (L2-hot) ----
    {
        const uint4* __restrict__ src = (const uint4*)Wpt;
        uint4* dst = (uint4*)Blds;
        // CC*PADK ushorts = 17408 B = 1088 x 16B
#pragma unroll
        for (int f = 0; f < 5; ++f) {
            int idx = f * 256 + tid;
            if (idx < (CC * PADK) / 8) dst[idx] = src[idx];
        }
    }

    // ---- stage A: pd tile fp32 -> bf16, coalesced float4 reads ----
    {
        // rows j0..j0+63, all K: one contiguous 32 KB region
        const float4* __restrict__ p4 =
            (const float4*)(pd + (((size_t)b * TT + i) * TT + j0) * KK);
#pragma unroll
        for (int it = 0; it < 8; ++it) {
            int f = it * 256 + tid;          // 0..2047 float4
            float4 val = p4[f];
            int j = f >> 5;                  // 32 float4 per row
            int kq = f & 31;
            uint2 u;
            u.x = (unsigned)f2bf(val.x) | ((unsigned)f2bf(val.y) << 16);
            u.y = (unsigned)f2bf(val.z) | ((unsigned)f2bf(val.w) << 16);
            *(uint2*)&Alds[j * PADK + kq * 4] = u;
        }
    }
    __syncthreads();

    // ---- MFMA main: wave handles 16 j-rows x 64 channels x K=128 ----
    const int wave = tid >> 6;
    const int lane = tid & 63;
    const int m = lane & 15;             // A: j-row low bits / B,C: channel
    const int kg = lane >> 4;            // k-group (8 k's each)

    float4v acc[4] = {{0.f,0.f,0.f,0.f},{0.f,0.f,0.f,0.f},
                      {0.f,0.f,0.f,0.f},{0.f,0.f,0.f,0.f}};
    const int arow = wave * 16 + m;
#pragma unroll
    for (int kt = 0; kt < 4; ++kt) {
        short8 a = *(const short8*)&Alds[arow * PADK + kt * 32 + kg * 8];
#pragma unroll
        for (int nt = 0; nt < 4; ++nt) {
            short8 bf = *(const short8*)&Blds[(nt * 16 + m) * PADK + kt * 32 + kg * 8];
            acc[nt] = __builtin_amdgcn_mfma_f32_16x16x32_bf16(a, bf, acc[nt], 0, 0, 0);
        }
    }

    // ---- epilogue: gelu + dot(W2) + store ----
    float w2v[4], qv[4];
#pragma unroll
    for (int nt = 0; nt < 4; ++nt) {
        int c = nt * 16 + m;
        w2v[nt] = W2[c];
        qv[nt] = qpb[((size_t)b * TT + i) * CC + c];
    }
    const float b2v = b2[0];

#pragma unroll
    for (int r = 0; r < 4; ++r) {
        const int j = j0 + wave * 16 + kg * 4 + r;   // C row = kg*4 + reg
        float s = 0.f;
#pragma unroll
        for (int nt = 0; nt < 4; ++nt) {
            float tv = acc[nt][r] + qv[nt] + kp[((size_t)b * TT + j) * CC + nt * 16 + m];
            float g = 0.5f * tv * (1.f + erff(tv * 0.70710678118654752f));
            s = fmaf(g, w2v[nt], s);
        }
#pragma unroll
        for (int off = 1; off < 16; off <<= 1) s += __shfl_xor(s, off);
        if (m == r && j <= i)
            wei[((size_t)b * TT + i) * TT + j] = (s + b2v) * 0.125f;
    }
}

// ---------------------------------------------------------------------------
// out_kernel: causal softmax over j in [0,i], then out[b,i,:] = p @ v
// ---------------------------------------------------------------------------
__device__ inline float wave_reduce_max(float m) {
#pragma unroll
    for (int off = 32; off > 0; off >>= 1) m = fmaxf(m, __shfl_down(m, off));
    return m;
}
__device__ inline float wave_reduce_sum(float s) {
#pragma unroll
    for (int off = 32; off > 0; off >>= 1) s += __shfl_down(s, off);
    return s;
}

__global__ __launch_bounds__(256) void out_kernel(
    const float* __restrict__ wei, const float* __restrict__ v,
    float* __restrict__ out)
{
    const int i = blockIdx.x;
    const int b = blockIdx.y;
    const int tid = threadIdx.x;
    const int wv = tid >> 6;
    const int lane = tid & 63;
    const int n = i + 1;

    __shared__ float p[TT];
    __shared__ float red[4];
    __shared__ float part[4][HH];

    float m = -1e30f;
    for (int jj = tid; jj < n; jj += 256) {
        float w = wei[((size_t)b * TT + i) * TT + jj];
        p[jj] = w;
        m = fmaxf(m, w);
    }
    m = wave_reduce_max(m);
    if (lane == 0) red[wv] = m;
    __syncthreads();
    const float M = fmaxf(fmaxf(red[0], red[1]), fmaxf(red[2], red[3]));
    __syncthreads();

    float s = 0.f;
    for (int jj = tid; jj < n; jj += 256) {
        float e = __expf(p[jj] - M);
        p[jj] = e;
        s += e;
    }
    s = wave_reduce_sum(s);
    if (lane == 0) red[wv] = s;
    __syncthreads();
    const float S = red[0] + red[1] + red[2] + red[3];
    const float inv = 1.f / S;

    float acc = 0.f, acc2 = 0.f;
    int jj = wv;
    for (; jj + 4 < n; jj += 8) {
        acc  = fmaf(p[jj],     v[((size_t)b * TT + jj) * HH + lane], acc);
        acc2 = fmaf(p[jj + 4], v[((size_t)b * TT + jj + 4) * HH + lane], acc2);
    }
    if (jj < n)
        acc = fmaf(p[jj], v[((size_t)b * TT + jj) * HH + lane], acc);
    acc += acc2;
    part[wv][lane] = acc;
    __syncthreads();
    if (tid < HH) {
        float r = (part[0][tid] + part[1][tid] + part[2][tid] + part[3][tid]) * inv;
        out[((size_t)b * TT + i) * HH + tid] = r;
    }
}

// ---------------------------------------------------------------------------
extern "C" void kernel_launch(void* const* d_in, const int* in_sizes, int n_in,
                              void* d_out, int out_size, void* d_ws, size_t ws_size,
                              hipStream_t stream)
{
    const float* x       = (const float*)d_in[0];
    const float* pos_emb = (const float*)d_in[1];
    const float* pd      = (const float*)d_in[2];
    const float* W1      = (const float*)d_in[3];
    const float* b1      = (const float*)d_in[4];
    const float* W2      = (const float*)d_in[5];
    const float* b2      = (const float*)d_in[6];
    const float* Wv      = (const float*)d_in[7];
    const float* bv      = (const float*)d_in[8];
    float* out = (float*)d_out;

    float* ws = (float*)d_ws;
    // layout (floats): Wpt [4608] | kp [65536] | qpb [65536] | v [65536] | wei [524288]
    unsigned short* Wpt = (unsigned short*)ws;          // 64*136 ushorts = 4352 floats
    float* kp  = ws + 4608;
    float* qpb = ws + 4608 + 65536;
    float* v   = ws + 4608 + 131072;
    float* wei = ws + 4608 + 196608;

    pack_kernel<<<dim3(32), dim3(256), 0, stream>>>(W1, Wpt);
    prep_kernel<<<dim3(BB * TT), dim3(64), 0, stream>>>(x, pos_emb, W1, b1, Wv, bv, kp, qpb, v);
    wei_kernel<<<dim3(TT / JT, TT, BB), dim3(256), 0, stream>>>(pd, Wpt, W2, b2, kp, qpb, wei);
    out_kernel<<<dim3(TT, BB), dim3(256), 0, stream>>>(wei, v, out);
}